// Round 6
// baseline (828.189 us; speedup 1.0000x reference)
//
#include <hip/hip_runtime.h>
#include <hip/hip_bf16.h>
#include <math.h>

// Problem constants
#define B_    8
#define CDIM  512
#define HW    4096
#define CI_   64
#define MT    32            // kv rows per tile
#define NTIL  (HW/MT)       // 128 tiles

typedef __attribute__((ext_vector_type(8))) short bf16x8;
typedef __attribute__((ext_vector_type(4))) float f32x4;
typedef __attribute__((ext_vector_type(16))) float f32x16;
typedef unsigned short u16;
typedef unsigned int   u32;

// fp32 -> bf16 bits with RNE rounding
__device__ __forceinline__ u32 bfr(float f) {
  u32 x = __float_as_uint(f);
  return (x + 0x7fffu + ((x >> 16) & 1u)) >> 16;
}
// packed 2xf32 -> bf16x2 (RNE) via HW instruction
__device__ __forceinline__ u32 cvtpk(float a, float b) {
  u32 r;
  asm("v_cvt_pk_bf16_f32 %0, %1, %2" : "=v"(r) : "v"(a), "v"(b));
  return r;
}

// ---------------- cast fp32 -> bf16 (weights) ----------------
__global__ void cast_bf16(const float* __restrict__ in, u16* __restrict__ out, int n) {
  int i = blockIdx.x * 256 + threadIdx.x;
  if (i < n) out[i] = (u16)bfr(in[i]);
}

// ---------------- transpose+cast: X [C,HW] f32 -> Xt [HW,C] bf16, per batch ----------------
__global__ void transpose_cast(const float* __restrict__ X, u16* __restrict__ Xt) {
  __shared__ float tile[32][33];
  const int n0 = blockIdx.x * 32, c0 = blockIdx.y * 32;
  const float* Xb = X + (size_t)blockIdx.z * CDIM * HW;
  u16* Xtb = Xt + (size_t)blockIdx.z * HW * CDIM;
  const int tx = threadIdx.x, ty = threadIdx.y; // block (32,8)
#pragma unroll
  for (int i = 0; i < 4; ++i)
    tile[ty + 8 * i][tx] = Xb[(size_t)(c0 + ty + 8 * i) * HW + n0 + tx];
  __syncthreads();
#pragma unroll
  for (int i = 0; i < 4; ++i)
    Xtb[(size_t)(n0 + ty + 8 * i) * CDIM + c0 + tx] = (u16)bfr(tile[tx][ty + 8 * i]);
}

// ---------------- NT GEMM: D[i,j] = (sum_k A[i,k]*B[j,k] + bias)*alpha, bf16 in/out ----------------
__global__ __launch_bounds__(256) void gemm_nt(
    const u16* __restrict__ A, const u16* __restrict__ Bm, u16* __restrict__ D,
    const float* __restrict__ bias, int biasRow, float alpha,
    int lda, int ldb, int ldd, long aBatch, long bBatch, long dBatch, int Kd)
{
  const int tid = threadIdx.x, wid = tid >> 6, lane = tid & 63;
  const int lr = lane & 15, lg = lane >> 4;
  const int i0 = blockIdx.x * 128 + wid * 32;
  const int j0 = blockIdx.y * 64;
  const u16* Ab = A + blockIdx.z * aBatch;
  const u16* Bb = Bm + blockIdx.z * bBatch;
  f32x4 acc[2][4];
#pragma unroll
  for (int rt = 0; rt < 2; ++rt)
#pragma unroll
    for (int ct = 0; ct < 4; ++ct) acc[rt][ct] = (f32x4){0.f, 0.f, 0.f, 0.f};

#pragma unroll 4
  for (int k0 = 0; k0 < Kd; k0 += 32) {
    bf16x8 af[2], bf[4];
#pragma unroll
    for (int rt = 0; rt < 2; ++rt)
      af[rt] = *(const bf16x8*)(Ab + (size_t)(i0 + rt * 16 + lr) * lda + k0 + lg * 8);
#pragma unroll
    for (int ct = 0; ct < 4; ++ct)
      bf[ct] = *(const bf16x8*)(Bb + (size_t)(j0 + ct * 16 + lr) * ldb + k0 + lg * 8);
#pragma unroll
    for (int rt = 0; rt < 2; ++rt)
#pragma unroll
      for (int ct = 0; ct < 4; ++ct)
        acc[rt][ct] = __builtin_amdgcn_mfma_f32_16x16x32_bf16(af[rt], bf[ct], acc[rt][ct], 0, 0, 0);
  }

  u16* Db = D + blockIdx.z * dBatch;
#pragma unroll
  for (int rt = 0; rt < 2; ++rt)
#pragma unroll
    for (int ct = 0; ct < 4; ++ct)
#pragma unroll
      for (int r = 0; r < 4; ++r) {
        int i = i0 + rt * 16 + lg * 4 + r;
        int j = j0 + ct * 16 + lr;
        float v = (acc[rt][ct][r] + (biasRow ? bias[i] : bias[j])) * alpha;
        Db[(size_t)i * ldd + j] = (u16)bfr(v);
      }
}

// ---------------- fused flash attention + gamma*attn + value ----------------
// No max-tracking (|S| ~ 2 << 88): P = exp(S), l = sum exp(S).
// Block = 4 waves = 64 q-rows x FULL C=512 (no c-duplication of exp).
// MT=32. QK: wave pair (nq=wid&1) computes the 32x32 S chunk (x2 MFMA dup,
// cheap); exp/P-write split by m-half (mh=wid>>1) -> ZERO exp duplication.
// PV: wave = c-quarter (cg=wid).
// K tile (4KB) + P tile (5KB) double-buffered; V tile (40KB, [c][m], 80B rows)
// single-buffered, 2 barriers/tile. All staging loads coalesced, issued one
// tile ahead into registers. LDS 59KB -> 2 blocks/CU.
__global__ __launch_bounds__(256, 2) void flash_attn(
    const u16* __restrict__ Q, const u16* __restrict__ K, const u16* __restrict__ V,
    const float* __restrict__ value, const float* __restrict__ gammap, float* __restrict__ out)
{
  __shared__ u16 Ks[2][32 * 72];   // [m=32][ci=64 +8pad]  144B rows
  __shared__ u16 Ps[2][64 * 40];   // [n=64][m=32 +8pad]   80B rows
  __shared__ u16 Vs[512 * 40];     // [c=512][m=32 +8pad]  80B rows

  const int b  = blockIdx.x & 7;
  const int nb = blockIdx.x >> 3;
  const int tid = threadIdx.x, wid = tid >> 6, lane = tid & 63;
  const int l31 = lane & 31, h = lane >> 5;
  const int nq = wid & 1, mh = wid >> 1;   // QK roles
  const int cg = wid;                       // PV c-quarter
  const int nb0 = nb * 64;

  const u16* Qb = Q + (size_t)b * HW * CI_;
  const u16* Kb = K + (size_t)b * HW * CI_;
  const u16* Vb = V + (size_t)b * CDIM * HW;

  // Q frags (B-op of swapped QK^T): col n = nb0 + nq*32 + l31, k = kk*16 + h*8 + j
  bf16x8 qf[4];
  {
    const u16* qp = Qb + (size_t)(nb0 + nq * 32 + l31) * CI_ + h * 8;
#pragma unroll
    for (int kk = 0; kk < 4; ++kk) qf[kk] = *(const bf16x8*)(qp + kk * 16);
  }

  f32x16 acc[2][4];
#pragma unroll
  for (int ng = 0; ng < 2; ++ng)
#pragma unroll
    for (int ct = 0; ct < 4; ++ct)
#pragma unroll
      for (int i = 0; i < 16; ++i) acc[ng][ct][i] = 0.f;
  float lp = 0.f;

  // staging maps (coalesced):
  // K tile 32x64: thr -> row tid>>3, 16B chunk (tid&7)*8   (8 thr x 16B = 128B/row)
  const int krow = tid >> 3, kcol = (tid & 7) * 8;
  // V tile 512x32: thr -> rows (tid>>2)+64*it, 16B chunk (tid&3)*8 (4 thr x 16B = 64B/row)
  const int vrow = tid >> 2, vcol = (tid & 3) * 8;
  uint4 kr, vr[8];

#define KLOAD(T) kr = *(const uint4*)(Kb + (size_t)((T) * MT + krow) * CI_ + kcol)
#define KWRITE(BUF) *(uint4*)(&Ks[BUF][krow * 72 + kcol]) = kr
#define VLOAD(T) do { \
    const u16* _s = Vb + (size_t)(T) * MT + vcol; \
    _Pragma("unroll") \
    for (int it = 0; it < 8; ++it) \
      vr[it] = *(const uint4*)(_s + (size_t)(vrow + it * 64) * HW); \
  } while (0)
#define VWRITE() do { \
    _Pragma("unroll") \
    for (int it = 0; it < 8; ++it) \
      *(uint4*)(&Vs[(vrow + it * 64) * 40 + vcol]) = vr[it]; \
  } while (0)

  // prologue: K tiles 0,1 staged/loaded; V tile 0 staged, tile 1 in regs
  KLOAD(0); KWRITE(0); KLOAD(1);
  VLOAD(0); VWRITE(); VLOAD(1);
  __syncthreads();

  for (int t = 0; t < NTIL; ++t) {
    const int par = t & 1;

    // ---- step 1: QK chunk + K staging + exp + packed P write ----
    f32x16 st;
#pragma unroll
    for (int i = 0; i < 16; ++i) st[i] = 0.f;
#pragma unroll
    for (int kk = 0; kk < 4; ++kk) {
      bf16x8 kf = *(const bf16x8*)(&Ks[par][l31 * 72 + kk * 16 + h * 8]);
      st = __builtin_amdgcn_mfma_f32_32x32x16_bf16(kf, qf[kk], st, 0, 0, 0);
    }
    if (t + 1 < NTIL) { KWRITE(par ^ 1); }   // Ks[par^1] readers finished before S1(t-1)
    if (t + 2 < NTIL) { KLOAD(t + 2); }

    {
      // lane holds S rows m = (r&3) + 8*(r>>2) + 4h for col n = nq*32+l31;
      // this wave exps r = mh*8 .. mh*8+7  (m-half mh) -> no duplication
      float p[8]; float rs = 0.f;
#pragma unroll
      for (int j = 0; j < 8; ++j) { p[j] = __expf(st[mh * 8 + j]); rs += p[j]; }
      lp += rs;
      const int nrow = nq * 32 + l31;
      char* pw = (char*)&Ps[par][0] + nrow * 80 + mh * 32 + 8 * h;
      uint2 w0, w1;
      w0.x = cvtpk(p[0], p[1]); w0.y = cvtpk(p[2], p[3]);   // m = mh*16+4h+0..3
      w1.x = cvtpk(p[4], p[5]); w1.y = cvtpk(p[6], p[7]);   // m = mh*16+8+4h+0..3
      *(uint2*)pw = w0;
      *(uint2*)(pw + 16) = w1;
    }
    __syncthreads();   // S1: Ps[par] ready

    // ---- step 3: PV over m=32 for this wave's 128 c ----
    bf16x8 paf[2][2];
#pragma unroll
    for (int ng = 0; ng < 2; ++ng)
#pragma unroll
      for (int kk = 0; kk < 2; ++kk)
        paf[ng][kk] = *(const bf16x8*)((const char*)&Ps[par][0] + (ng * 32 + l31) * 80 + kk * 32 + h * 16);

    __builtin_amdgcn_s_setprio(1);
#pragma unroll
    for (int kk = 0; kk < 2; ++kk)
#pragma unroll
      for (int ct = 0; ct < 4; ++ct) {
        bf16x8 vf = *(const bf16x8*)((const char*)&Vs[0] + (cg * 128 + ct * 32 + l31) * 80 + kk * 32 + h * 16);
        acc[0][ct] = __builtin_amdgcn_mfma_f32_32x32x16_bf16(vf, paf[0][kk], acc[0][ct], 0, 0, 0);
        acc[1][ct] = __builtin_amdgcn_mfma_f32_32x32x16_bf16(vf, paf[1][kk], acc[1][ct], 0, 0, 0);
      }
    __builtin_amdgcn_s_setprio(0);
    __syncthreads();   // S2: all PV reads of Vs done

    // ---- step 5: V staging for t+1 (regs loaded at t-1); issue loads for t+2 ----
    if (t + 1 < NTIL) {
      VWRITE();
      if (t + 2 < NTIL) VLOAD(t + 2);
    }
  }

  // ---- epilogue: combine l partials, out = gamma*acc/l + value ----
  lp += __shfl_xor(lp, 32);              // combine h halves
  float* lred = (float*)&Ks[0][0];       // [wid][32]
  if (lane < 32) lred[wid * 32 + l31] = lp;
  __syncthreads();

  const float g = gammap[0];
  float* Tls = (float*)&Vs[wid * 2176];  // per-wave 32c x 33n f32 (4352B)
  const size_t obase = (size_t)b * CDIM * HW;
#pragma unroll
  for (int ng = 0; ng < 2; ++ng) {
    // l[n = ng*32+l31] = sum over mh waves (wid = 2*mh + ng)
    const float ri = g / (lred[ng * 32 + l31] + lred[(2 + ng) * 32 + l31]);
#pragma unroll
    for (int ct = 0; ct < 4; ++ct) {
      // acc: col(lane l31) = n, reg r -> c-row; transpose via LDS for coalesced out
#pragma unroll
      for (int r = 0; r < 16; ++r) {
        int cc = (r & 3) + 8 * (r >> 2) + 4 * h;
        Tls[cc * 33 + l31] = acc[ng][ct][r] * ri;
      }
#pragma unroll
      for (int pp = 0; pp < 16; ++pp) {
        float v = Tls[l31 * 33 + 2 * pp + h];
        int n = nb0 + ng * 32 + 2 * pp + h;
        int c = cg * 128 + ct * 32 + l31;
        size_t idx = obase + (size_t)n * CDIM + c;
        out[idx] = v + value[idx];
      }
    }
  }
}

extern "C" void kernel_launch(void* const* d_in, const int* in_sizes, int n_in,
                              void* d_out, int out_size, void* d_ws, size_t ws_size,
                              hipStream_t stream) {
  const float* query = (const float*)d_in[0];
  const float* key   = (const float*)d_in[1];
  const float* value = (const float*)d_in[2];
  const float* Wq    = (const float*)d_in[3];
  const float* bq    = (const float*)d_in[4];
  const float* Wk    = (const float*)d_in[5];
  const float* bk    = (const float*)d_in[6];
  const float* Wv    = (const float*)d_in[7];
  const float* bv    = (const float*)d_in[8];
  const float* gamma = (const float*)d_in[9];

  char* ws = (char*)d_ws;
  u16* XT  = (u16*)(ws);               // 33,554,432 B  [B,HW,C] bf16
  u16* Qb  = (u16*)(ws + 33554432);    //  4,194,304 B  [B,HW,CI]
  u16* Kb  = (u16*)(ws + 37748736);    //  4,194,304 B  [B,HW,CI]
  u16* Vb  = (u16*)(ws + 41943040);    // 33,554,432 B  [B,C,HW]
  u16* WQb = (u16*)(ws + 75497472);    //     65,536 B
  u16* WKb = (u16*)(ws + 75563008);    //     65,536 B
  u16* WVb = (u16*)(ws + 75628544);    //    524,288 B

  cast_bf16<<<(32768 + 255) / 256, 256, 0, stream>>>(Wq, WQb, 32768);
  cast_bf16<<<(32768 + 255) / 256, 256, 0, stream>>>(Wk, WKb, 32768);
  cast_bf16<<<(262144 + 255) / 256, 256, 0, stream>>>(Wv, WVb, 262144);

  dim3 tgrid(HW / 32, CDIM / 32, B_);
  dim3 tblk(32, 8);

  // Q = (query^T Wq^T + bq) * (1/8)   -> [B,HW,CI]
  transpose_cast<<<tgrid, tblk, 0, stream>>>(query, XT);
  gemm_nt<<<dim3(HW / 128, 1, B_), 256, 0, stream>>>(
      XT, WQb, Qb, bq, 0, 0.125f, CDIM, CDIM, CI_,
      (long)HW * CDIM, 0L, (long)HW * CI_, CDIM);

  // K = key^T Wk^T + bk               -> [B,HW,CI]
  transpose_cast<<<tgrid, tblk, 0, stream>>>(key, XT);
  gemm_nt<<<dim3(HW / 128, 1, B_), 256, 0, stream>>>(
      XT, WKb, Kb, bk, 0, 1.0f, CDIM, CDIM, CI_,
      (long)HW * CDIM, 0L, (long)HW * CI_, CDIM);

  // V^T = Wv (value^T)^T + bv  stored [B, C, HW]
  transpose_cast<<<tgrid, tblk, 0, stream>>>(value, XT);
  gemm_nt<<<dim3(CDIM / 128, HW / 64, B_), 256, 0, stream>>>(
      WVb, XT, Vb, bv, 1, 1.0f, CDIM, CDIM, HW,
      0L, (long)HW * CDIM, (long)CDIM * HW, CDIM);

  // Fused flash attention + epilogue
  flash_attn<<<512, 256, 0, stream>>>(Qb, Kb, Vb, value, gamma, (float*)d_out);
}

// Round 7
// 409.999 us; speedup vs baseline: 2.0200x; 2.0200x over previous
//
#include <hip/hip_runtime.h>
#include <hip/hip_bf16.h>
#include <math.h>

// Problem constants
#define B_    8
#define CDIM  512
#define HW    4096
#define CI_   64
#define MT    64            // kv rows per tile
#define NTIL  (HW/MT)       // 64 tiles
#define KROW  72            // LDS row stride (u16): 144B -> conflict-free b128
#define VROW  72

typedef __attribute__((ext_vector_type(8))) short bf16x8;
typedef __attribute__((ext_vector_type(4))) float f32x4;
typedef __attribute__((ext_vector_type(16))) float f32x16;
typedef unsigned short u16;
typedef unsigned int   u32;

union fragu { bf16x8 v; u32 w[4]; };

// fp32 -> bf16 bits with RNE rounding
__device__ __forceinline__ u32 bfr(float f) {
  u32 x = __float_as_uint(f);
  return (x + 0x7fffu + ((x >> 16) & 1u)) >> 16;
}
// packed 2xf32 -> bf16x2 (RNE) via HW instruction
__device__ __forceinline__ u32 cvtpk(float a, float b) {
  u32 r;
  asm("v_cvt_pk_bf16_f32 %0, %1, %2" : "=v"(r) : "v"(a), "v"(b));
  return r;
}

// ---------------- cast fp32 -> bf16 (weights) ----------------
__global__ void cast_bf16(const float* __restrict__ in, u16* __restrict__ out, int n) {
  int i = blockIdx.x * 256 + threadIdx.x;
  if (i < n) out[i] = (u16)bfr(in[i]);
}

// ---------------- transpose+cast: X [C,HW] f32 -> Xt [HW,C] bf16, per batch ----------------
__global__ void transpose_cast(const float* __restrict__ X, u16* __restrict__ Xt) {
  __shared__ float tile[32][33];
  const int n0 = blockIdx.x * 32, c0 = blockIdx.y * 32;
  const float* Xb = X + (size_t)blockIdx.z * CDIM * HW;
  u16* Xtb = Xt + (size_t)blockIdx.z * HW * CDIM;
  const int tx = threadIdx.x, ty = threadIdx.y; // block (32,8)
#pragma unroll
  for (int i = 0; i < 4; ++i)
    tile[ty + 8 * i][tx] = Xb[(size_t)(c0 + ty + 8 * i) * HW + n0 + tx];
  __syncthreads();
#pragma unroll
  for (int i = 0; i < 4; ++i)
    Xtb[(size_t)(n0 + ty + 8 * i) * CDIM + c0 + tx] = (u16)bfr(tile[tx][ty + 8 * i]);
}

// ---------------- NT GEMM: D[i,j] = (sum_k A[i,k]*B[j,k] + bias)*alpha, bf16 in/out ----------------
__global__ __launch_bounds__(256) void gemm_nt(
    const u16* __restrict__ A, const u16* __restrict__ Bm, u16* __restrict__ D,
    const float* __restrict__ bias, int biasRow, float alpha,
    int lda, int ldb, int ldd, long aBatch, long bBatch, long dBatch, int Kd)
{
  const int tid = threadIdx.x, wid = tid >> 6, lane = tid & 63;
  const int lr = lane & 15, lg = lane >> 4;
  const int i0 = blockIdx.x * 128 + wid * 32;
  const int j0 = blockIdx.y * 64;
  const u16* Ab = A + blockIdx.z * aBatch;
  const u16* Bb = Bm + blockIdx.z * bBatch;
  f32x4 acc[2][4];
#pragma unroll
  for (int rt = 0; rt < 2; ++rt)
#pragma unroll
    for (int ct = 0; ct < 4; ++ct) acc[rt][ct] = (f32x4){0.f, 0.f, 0.f, 0.f};

#pragma unroll 4
  for (int k0 = 0; k0 < Kd; k0 += 32) {
    bf16x8 af[2], bf[4];
#pragma unroll
    for (int rt = 0; rt < 2; ++rt)
      af[rt] = *(const bf16x8*)(Ab + (size_t)(i0 + rt * 16 + lr) * lda + k0 + lg * 8);
#pragma unroll
    for (int ct = 0; ct < 4; ++ct)
      bf[ct] = *(const bf16x8*)(Bb + (size_t)(j0 + ct * 16 + lr) * ldb + k0 + lg * 8);
#pragma unroll
    for (int rt = 0; rt < 2; ++rt)
#pragma unroll
      for (int ct = 0; ct < 4; ++ct)
        acc[rt][ct] = __builtin_amdgcn_mfma_f32_16x16x32_bf16(af[rt], bf[ct], acc[rt][ct], 0, 0, 0);
  }

  u16* Db = D + blockIdx.z * dBatch;
#pragma unroll
  for (int rt = 0; rt < 2; ++rt)
#pragma unroll
    for (int ct = 0; ct < 4; ++ct)
#pragma unroll
      for (int r = 0; r < 4; ++r) {
        int i = i0 + rt * 16 + lg * 4 + r;
        int j = j0 + ct * 16 + lr;
        float v = (acc[rt][ct][r] + (biasRow ? bias[i] : bias[j])) * alpha;
        Db[(size_t)i * ldd + j] = (u16)bfr(v);
      }
}

// ---------------- fused flash attention + gamma*attn + value ----------------
// R4 structure (measured 278us, no spill) + T12 pack path (cvt_pk + permlane32_swap).
// No max-tracking (|S| ~ 2 << 88): P = exp(S), l = sum exp(S).
// Each WAVE independently owns 64 q-rows x 128 c-cols; P stays in registers.
// Block = 4 waves = 256 q-rows x 128 c. Grid = 8 batch x 16 rowblk x 4 cslice.
// K,V tiles reg-staged into padded LDS (dbuf), ONE barrier per tile.
__global__ __launch_bounds__(256, 2) void flash_attn(
    const u16* __restrict__ Q, const u16* __restrict__ K, const u16* __restrict__ V,
    const float* __restrict__ value, const float* __restrict__ gammap, float* __restrict__ out)
{
  __shared__ u16 Ks[2][64 * KROW];    // 2 x 9.2 KB  [m=64][ci=64 +pad]
  __shared__ u16 Vs[2][128 * VROW];   // 2 x 18.4 KB [c=128][m=64 +pad]

  const int b  = blockIdx.x & 7;
  const int rb = (blockIdx.x >> 3) & 15;
  const int ch = blockIdx.x >> 7;
  const int tid = threadIdx.x, wid = tid >> 6, lane = tid & 63;
  const int l31 = lane & 31, h = lane >> 5;

  const int n0 = rb * 256 + wid * 64;   // wave q-row base
  const int c0 = ch * 128;              // block c base

  const u16* Qb = Q + (size_t)b * HW * CI_;
  const u16* Kb = K + (size_t)b * HW * CI_;
  const u16* Vb = V + (size_t)b * CDIM * HW + (size_t)c0 * HW;

  // Q B-frags: col n = n0 + ng*32 + l31, k = kk*16 + h*8 + j
  bf16x8 qf[2][4];
#pragma unroll
  for (int ng = 0; ng < 2; ++ng)
#pragma unroll
    for (int kk = 0; kk < 4; ++kk)
      qf[ng][kk] = *(const bf16x8*)(Qb + (size_t)(n0 + ng * 32 + l31) * CI_ + kk * 16 + h * 8);

  f32x16 acc[2][4];
#pragma unroll
  for (int ng = 0; ng < 2; ++ng)
#pragma unroll
    for (int ct = 0; ct < 4; ++ct)
#pragma unroll
      for (int i = 0; i < 16; ++i) acc[ng][ct][i] = 0.f;
  float lp0 = 0.f, lp1 = 0.f;

  // staging maps: K tile 8KB (4 thr/row x 2 b128), V tile 16KB (2 thr/row x 4 b128)
  const int krow_ = tid >> 2, kcol = (tid & 3) * 8;
  const int vrow_ = tid >> 1, vcol = (tid & 1) * 32;
  uint4 kr[2], vr[4];

#define SISSUE(T) do { \
    const u16* kp_ = Kb + (size_t)((T) * MT + krow_) * CI_ + kcol; \
    kr[0] = *(const uint4*)kp_; \
    kr[1] = *(const uint4*)(kp_ + 32); \
    const u16* vp_ = Vb + (size_t)vrow_ * HW + (T) * MT + vcol; \
    _Pragma("unroll") \
    for (int j = 0; j < 4; ++j) vr[j] = *(const uint4*)(vp_ + j * 8); \
  } while (0)

#define SWRITE(BUF) do { \
    *(uint4*)(&Ks[BUF][krow_ * KROW + kcol]) = kr[0]; \
    *(uint4*)(&Ks[BUF][krow_ * KROW + kcol + 32]) = kr[1]; \
    _Pragma("unroll") \
    for (int j = 0; j < 4; ++j) \
      *(uint4*)(&Vs[BUF][vrow_ * VROW + vcol + j * 8]) = vr[j]; \
  } while (0)

  SISSUE(0); SWRITE(0);
  __syncthreads();

  for (int t = 0; t < NTIL; ++t) {
    const int par = t & 1;
    if (t + 1 < NTIL) SISSUE(t + 1);   // next-tile global loads; land during compute

#pragma unroll
    for (int s = 0; s < 2; ++s) {      // m-strip of 32 within the 64-m tile
      // K A-frags: row m = s*32 + l31, k = kk*16 + h*8 + j
      bf16x8 kf[4];
#pragma unroll
      for (int kk = 0; kk < 4; ++kk)
        kf[kk] = *(const bf16x8*)(&Ks[par][(s * 32 + l31) * KROW + kk * 16 + h * 8]);

      bf16x8 pa[2][2];                 // [ng][kk-local] PV B-frags for this strip
#pragma unroll
      for (int ng = 0; ng < 2; ++ng) {
        f32x16 st;
#pragma unroll
        for (int i = 0; i < 16; ++i) st[i] = 0.f;
#pragma unroll
        for (int kk = 0; kk < 4; ++kk)
          st = __builtin_amdgcn_mfma_f32_32x32x16_bf16(kf[kk], qf[ng][kk], st, 0, 0, 0);

        // exp + row-sum partial (lane holds 16 of 32 m-values for row n=l31)
        float p[16]; float rs = 0.f;
#pragma unroll
        for (int r = 0; r < 16; ++r) { p[r] = __expf(st[r]); rs += p[r]; }
        if (ng == 0) lp0 += rs; else lp1 += rs;

        // T12 pack: quads m(r) = (r&3) + 8*(r>>2) + 4h (within strip)
        u32 qa0 = cvtpk(p[0],  p[1]),  qa1 = cvtpk(p[2],  p[3]);   // m 4h+0..3
        u32 qb0 = cvtpk(p[4],  p[5]),  qb1 = cvtpk(p[6],  p[7]);   // m 8+4h+0..3
        u32 qc0 = cvtpk(p[8],  p[9]),  qc1 = cvtpk(p[10], p[11]);  // m 16+4h+0..3
        u32 qd0 = cvtpk(p[12], p[13]), qd1 = cvtpk(p[14], p[15]);  // m 24+4h+0..3
        // in-place half swap: a'.hi(lane>=32) = b[lane-32]; b'.lo(lane<32) = a[lane+32]
        // h=0 ends with {own qa, partner qa} = m0..7; h=1 with {partner qb, own qb} = m8..15
        asm("v_permlane32_swap_b32 %0, %1" : "+v"(qa0), "+v"(qb0));
        asm("v_permlane32_swap_b32 %0, %1" : "+v"(qa1), "+v"(qb1));
        asm("v_permlane32_swap_b32 %0, %1" : "+v"(qc0), "+v"(qd0));
        asm("v_permlane32_swap_b32 %0, %1" : "+v"(qc1), "+v"(qd1));
        fragu f0; f0.w[0] = qa0; f0.w[1] = qa1; f0.w[2] = qb0; f0.w[3] = qb1;
        pa[ng][0] = f0.v;
        fragu f1; f1.w[0] = qc0; f1.w[1] = qc1; f1.w[2] = qd0; f1.w[3] = qd1;
        pa[ng][1] = f1.v;
      }

      // PV partial for this strip: kk = 2s + kkl
      __builtin_amdgcn_s_setprio(1);
#pragma unroll
      for (int ct = 0; ct < 4; ++ct)
#pragma unroll
        for (int kkl = 0; kkl < 2; ++kkl) {
          bf16x8 vf = *(const bf16x8*)(&Vs[par][(ct * 32 + l31) * VROW + (2 * s + kkl) * 16 + h * 8]);
          acc[0][ct] = __builtin_amdgcn_mfma_f32_32x32x16_bf16(vf, pa[0][kkl], acc[0][ct], 0, 0, 0);
          acc[1][ct] = __builtin_amdgcn_mfma_f32_32x32x16_bf16(vf, pa[1][kkl], acc[1][ct], 0, 0, 0);
        }
      __builtin_amdgcn_s_setprio(0);
    }

    if (t + 1 < NTIL) SWRITE((t + 1) & 1);
    __syncthreads();   // single barrier: protects dbuf parity both directions
  }

  // ---- epilogue: per-wave LDS transpose so value/out stay coalesced ----
  __syncthreads();   // everyone done with Ks/Vs; reuse as scratch
  float* Tls = (float*)((char*)&Vs[0][0] + wid * 4352);  // 32c x 33n f32 = 4224B per wave
  const float g = gammap[0];
  const float ls0 = lp0 + __shfl_xor(lp0, 32);
  const float ls1 = lp1 + __shfl_xor(lp1, 32);
  const float ri0 = g / ls0, ri1 = g / ls1;   // gamma folded; lane's n = l31 (per ng)
  const size_t obase = (size_t)b * CDIM * HW;
#pragma unroll
  for (int ng = 0; ng < 2; ++ng) {
    const float ri = ng ? ri1 : ri0;
#pragma unroll
    for (int ct = 0; ct < 4; ++ct) {
      // write: Tls[c_local][n_local]
#pragma unroll
      for (int r = 0; r < 16; ++r) {
        int cc = (r & 3) + 8 * (r >> 2) + 4 * h;
        Tls[cc * 33 + l31] = acc[ng][ct][r] * ri;
      }
      // read coalesced: lane -> c = l31, n = 2p + h
#pragma unroll
      for (int p = 0; p < 16; ++p) {
        float v = Tls[l31 * 33 + 2 * p + h];
        int n = n0 + ng * 32 + 2 * p + h;
        int c = c0 + ct * 32 + l31;
        size_t idx = obase + (size_t)n * CDIM + c;
        out[idx] = v + value[idx];
      }
    }
  }
}

extern "C" void kernel_launch(void* const* d_in, const int* in_sizes, int n_in,
                              void* d_out, int out_size, void* d_ws, size_t ws_size,
                              hipStream_t stream) {
  const float* query = (const float*)d_in[0];
  const float* key   = (const float*)d_in[1];
  const float* value = (const float*)d_in[2];
  const float* Wq    = (const float*)d_in[3];
  const float* bq    = (const float*)d_in[4];
  const float* Wk    = (const float*)d_in[5];
  const float* bk    = (const float*)d_in[6];
  const float* Wv    = (const float*)d_in[7];
  const float* bv    = (const float*)d_in[8];
  const float* gamma = (const float*)d_in[9];

  char* ws = (char*)d_ws;
  u16* XT  = (u16*)(ws);               // 33,554,432 B  [B,HW,C] bf16
  u16* Qb  = (u16*)(ws + 33554432);    //  4,194,304 B  [B,HW,CI]
  u16* Kb  = (u16*)(ws + 37748736);    //  4,194,304 B  [B,HW,CI]
  u16* Vb  = (u16*)(ws + 41943040);    // 33,554,432 B  [B,C,HW]
  u16* WQb = (u16*)(ws + 75497472);    //     65,536 B
  u16* WKb = (u16*)(ws + 75563008);    //     65,536 B
  u16* WVb = (u16*)(ws + 75628544);    //    524,288 B

  cast_bf16<<<(32768 + 255) / 256, 256, 0, stream>>>(Wq, WQb, 32768);
  cast_bf16<<<(32768 + 255) / 256, 256, 0, stream>>>(Wk, WKb, 32768);
  cast_bf16<<<(262144 + 255) / 256, 256, 0, stream>>>(Wv, WVb, 262144);

  dim3 tgrid(HW / 32, CDIM / 32, B_);
  dim3 tblk(32, 8);

  // Q = (query^T Wq^T + bq) * (1/8)   -> [B,HW,CI]
  transpose_cast<<<tgrid, tblk, 0, stream>>>(query, XT);
  gemm_nt<<<dim3(HW / 128, 1, B_), 256, 0, stream>>>(
      XT, WQb, Qb, bq, 0, 0.125f, CDIM, CDIM, CI_,
      (long)HW * CDIM, 0L, (long)HW * CI_, CDIM);

  // K = key^T Wk^T + bk               -> [B,HW,CI]
  transpose_cast<<<tgrid, tblk, 0, stream>>>(key, XT);
  gemm_nt<<<dim3(HW / 128, 1, B_), 256, 0, stream>>>(
      XT, WKb, Kb, bk, 0, 1.0f, CDIM, CDIM, CI_,
      (long)HW * CDIM, 0L, (long)HW * CI_, CDIM);

  // V^T = Wv (value^T)^T + bv  stored [B, C, HW]
  transpose_cast<<<tgrid, tblk, 0, stream>>>(value, XT);
  gemm_nt<<<dim3(CDIM / 128, HW / 64, B_), 256, 0, stream>>>(
      WVb, XT, Vb, bv, 1, 1.0f, CDIM, CDIM, HW,
      0L, (long)HW * CDIM, (long)CDIM * HW, CDIM);

  // Fused flash attention + epilogue
  flash_attn<<<512, 256, 0, stream>>>(Qb, Kb, Vb, value, gamma, (float*)d_out);
}